// Round 6
// baseline (248.056 us; speedup 1.0000x reference)
//
#include <hip/hip_runtime.h>
#include <stdint.h>

#define BB 32
#define SS 512
#define HH 256
#define MM (BB*SS)     // 16384 rows
#define MAXMEL 2048

typedef _Float16 f16;
typedef _Float16 f16x4 __attribute__((ext_vector_type(4)));
typedef _Float16 f16x8 __attribute__((ext_vector_type(8)));
typedef float    f32x16 __attribute__((ext_vector_type(16)));

#define BAR()  asm volatile("s_barrier" ::: "memory")
#define VMW0() asm volatile("s_waitcnt vmcnt(0)" ::: "memory")

// X''' layout: [cb 16][rp MM/2][slot 4][8 f16]
// slot = (2*(row&1) + g) ^ ((rp>>1)&3), g = (chan>>3)&1, cb = chan>>4.
// A wave's 16-lane read phase covers 8 rowpairs x 2 parities -> each 16B
// granule hit exactly 2x -> bank-conflict-free (2-way is free, m136).
__device__ __forceinline__ size_t xoff(int row, int chan) {
  int cb = chan >> 4, g = (chan >> 3) & 1, e = chan & 7;
  int rp = row >> 1, par = row & 1;
  int slot = (2 * par + g) ^ ((rp >> 1) & 3);
  return (((size_t)cb * (MM / 2) + rp) * 4 + slot) * 8 + e;
}

// LDS map (bytes): B @0 (24576 = [tap3][p2][cp64][slot4][16B]),
//                  A @24576 (8192 = [p2][rp64][slot4][16B]), zeros @32768 (64B)
#define BOFF  0
#define AOFF  24576
#define AZ    32768
#define LDSSZ 32832
#define WSZ   ((size_t)768 * 256)     // f16 elems per packed weight plane

// ---------------- conv1d (K=3 SAME, 256->256), split-f16 MFMA ----------------
// 64-row x 128-col block, 4 waves (2x2), wave tile 32x64 (2 n-frags 32x32x16).
// 16 steps of (16 chans x 3 taps). Single-buffered A+B (32.8KB -> 4 blocks/CU).
// 3-product split: Ahi*Bhi + Ahi*Blo + Alo*Bhi (~f32 accuracy).
// Wave 0 stages A (8 DMA), waves 1-3 stage B (8 DMA each) -> vmcnt(0) exact.
__global__ __launch_bounds__(256, 4) void conv64(
    const f16* __restrict__ X0h, const f16* __restrict__ X0l,
    const f16* __restrict__ X1h_, const f16* __restrict__ X1l_,
    const f16* __restrict__ W0h, const f16* __restrict__ W0l,
    const f16* __restrict__ W1h, const f16* __restrict__ W1l,
    const float* __restrict__ bias0, const float* __restrict__ bias1,
    f16* __restrict__ Y0h, f16* __restrict__ Y0l,
    f16* __restrict__ Y1h, f16* __restrict__ Y1l)
{
  __shared__ __align__(16) unsigned char smem[LDSSZ];
  const int tid = threadIdx.x;
  const int lane = tid & 63, wid = tid >> 6;
  const int bm = blockIdx.x, bn = blockIdx.y, bz = blockIdx.z;
  const int l31 = lane & 31, half = lane >> 5;
  const int hx4 = half << 4;
  const int wr = wid >> 1, wc = wid & 1;

  const f16* Xh = bz ? X1h_ : X0h;
  const f16* Xl = bz ? X1l_ : X0l;
  const f16* Wh = bz ? W1h : W0h;
  const f16* Wl = bz ? W1l : W0l;

  // ---- stage descriptors: 8 DMA per thread ----
  // wave 0: A (j=0..7: p = j>>2, seg = j&3); waves 1-3: B (j-8: tap,p,q4)
  const f16* sb[8]; int sdst[8];
  size_t sstr;
  #pragma unroll
  for (int i = 0; i < 8; ++i) {
    int j = wid * 8 + i;
    if (j < 8) {                       // A: 4 segs x 32 rows x 2 planes
      int p = j >> 2, seg = j & 3;
      int rowstart = bm * 64 - 32 + seg * 32;
      rowstart = rowstart < 0 ? 0 : (rowstart > MM - 32 ? MM - 32 : rowstart);
      sb[i]   = (p ? Xl : Xh) + (size_t)(rowstart >> 1) * 32 + lane * 8;
      sdst[i] = AOFF + p * 4096 + seg * 1024 + lane * 16;
    } else {                           // B: [tap][p][q4 of cp-range]
      int jj = j - 8;
      int tap = jj >> 3, rem = jj & 7;
      int p = rem >> 2, q4 = rem & 3;
      sb[i]   = (p ? Wl : Wh) + ((size_t)((bn * 16) * 3 + tap) * 256 + q4 * 64 + lane) * 8;
      sdst[i] = tap * 8192 + p * 4096 + q4 * 1024 + lane * 16;
    }
  }
  sstr = (wid == 0) ? (size_t)(MM / 2) * 32 : (size_t)3 * 256 * 8;

  // ---- fragment read addresses ----
  int a_addr[3][2];                    // [tap][p]
  #pragma unroll
  for (int tap = 0; tap < 3; ++tap) {
    int row_l = wr * 32 + l31;
    int sseq = (bm & 7) * 64 + row_l + tap - 1;
    bool valid = (unsigned)sseq < 512u;
    int lrow = row_l + tap + 31;       // local (rowstart-relative) row
    int rp = lrow >> 1, par = lrow & 1;
    int slot0 = (2 * par) ^ ((rp >> 1) & 3);
    int base = AOFF + rp * 64 + slot0 * 16;
    a_addr[tap][0] = valid ? base : AZ;
    a_addr[tap][1] = valid ? (base + 4096) : AZ;
  }
  int b_base[2];                       // [n]
  #pragma unroll
  for (int n = 0; n < 2; ++n) {
    int col = wc * 64 + n * 32 + l31;
    int cp = col >> 1, cpar = col & 1;
    int slot0 = (2 * cpar) ^ ((cp >> 1) & 3);
    b_base[n] = cp * 64 + slot0 * 16;
  }

  f32x16 acc[2];
  acc[0] = (f32x16)0.f;
  acc[1] = (f32x16)0.f;

  auto STAGE = [&](int step) {
    #pragma unroll
    for (int i = 0; i < 8; ++i)
      __builtin_amdgcn_global_load_lds(
        (const __attribute__((address_space(1))) void*)(sb[i] + (size_t)step * sstr),
        (__attribute__((address_space(3))) void*)(smem + sdst[i]), 16, 0, 0);
  };

  auto COMP = [&]() {
    #pragma unroll
    for (int tap = 0; tap < 3; ++tap) {
      f16x8 av[2], bv[2][2];
      #pragma unroll
      for (int p = 0; p < 2; ++p) {
        av[p] = *(const f16x8*)(smem + (a_addr[tap][p] ^ hx4));
        #pragma unroll
        for (int n = 0; n < 2; ++n)
          bv[p][n] = *(const f16x8*)(smem + (tap * 8192 + p * 4096 + (b_base[n] ^ hx4)));
      }
      #pragma unroll
      for (int n = 0; n < 2; ++n) {
        acc[n] = __builtin_amdgcn_mfma_f32_32x32x16_f16(av[0], bv[0][n], acc[n], 0, 0, 0);
        acc[n] = __builtin_amdgcn_mfma_f32_32x32x16_f16(av[0], bv[1][n], acc[n], 0, 0, 0);
        acc[n] = __builtin_amdgcn_mfma_f32_32x32x16_f16(av[1], bv[0][n], acc[n], 0, 0, 0);
      }
    }
  };

  if (tid < 4)
    *(float4*)(smem + AZ + tid * 16) = make_float4(0.f, 0.f, 0.f, 0.f);
  STAGE(0);
  __syncthreads();                     // drains vmcnt+lgkm: step0 + zeros visible

  for (int i = 0; i < 16; ++i) {
    COMP();
    if (i < 15) {
      BAR();                           // all waves done reading the buffers
      STAGE(i + 1);
      VMW0();                          // own 8 DMA landed
      BAR();                           // everyone's landed
    }
  }

  // epilogue: +bias, ReLU, split, store planes in X''' layout.
  // C/D layout: col=lane&31, row=(reg&3)+8*(reg>>2)+4*(lane>>5)
  const float* bias = bz ? bias1 : bias0;
  f16* Yh = bz ? Y1h : Y0h;
  f16* Yl = bz ? Y1l : Y0l;
  #pragma unroll
  for (int n = 0; n < 2; ++n) {
    int colg = bn * 128 + wc * 64 + n * 32 + l31;
    float bvs = bias[colg];
    int cb = colg >> 4, g = (colg >> 3) & 1, e = colg & 7;
    #pragma unroll
    for (int r = 0; r < 16; ++r) {
      int rowl = (r & 3) + 8 * (r >> 2) + 4 * half;
      int rowg = bm * 64 + wr * 32 + rowl;
      float v = fmaxf(acc[n][r] + bvs, 0.f);
      f16 h = (f16)v;
      f16 l = (f16)(v - (float)h);
      int rp = rowg >> 1, par = rowg & 1;
      int slot = (2 * par + g) ^ ((rp >> 1) & 3);
      size_t o = (((size_t)cb * (MM / 2) + rp) * 4 + slot) * 8 + e;
      Yh[o] = h;
      Yl[o] = l;
    }
  }
}

// ---------------- weight pack+split, all 6 weights in one launch ----------------
// per plane, 16B-unit idx = (((bn*16+step)*3+tap)*256 + cp*4 + slot)
__global__ __launch_bounds__(256) void wsplit6(
    const float* __restrict__ W0, const float* __restrict__ W1,
    const float* __restrict__ W2, const float* __restrict__ W3,
    const float* __restrict__ W4, const float* __restrict__ W5,
    f16* __restrict__ Wt)
{
  int z = blockIdx.y;
  const float* W = z==0?W0 : z==1?W1 : z==2?W2 : z==3?W3 : z==4?W4 : W5;
  f16* Thi = Wt + (size_t)z * 2 * WSZ;
  f16* Tlo = Thi + WSZ;
  int id = blockIdx.x * 256 + threadIdx.x;    // [0, 24576)
  int slot = id & 3, cp = (id >> 2) & 63;
  int t3 = id >> 8;                           // [0, 96)
  int tap = t3 % 3, bs = t3 / 3;
  int step = bs & 15, bnn = bs >> 4;
  int s2 = slot ^ ((cp >> 1) & 3);
  int cpar = s2 >> 1, g = s2 & 1;
  int col = cp * 2 + cpar;
  int chan = step * 16 + g * 8;
  int colg = bnn * 128 + col;
  f16x8 hi, lo;
  #pragma unroll
  for (int e = 0; e < 8; ++e) {
    float w = W[(size_t)(tap * 256 + chan + e) * 256 + colg];
    f16 h = (f16)w;
    hi[e] = h;
    lo[e] = (f16)(w - (float)h);
  }
  *(f16x8*)(Thi + (size_t)id * 8) = hi;
  *(f16x8*)(Tlo + (size_t)id * 8) = lo;
}

// ---------------- split f32 -> hi/lo planes (X''' layout) ----------------
__global__ __launch_bounds__(256) void split2(
    const float* __restrict__ X, f16* __restrict__ Hi, f16* __restrict__ Lo)
{
  int id = blockIdx.x * 256 + threadIdx.x;    // [0, MM*32)
  int row = id >> 5, chan = (id & 31) * 8;
  const float* src = X + (size_t)row * 256 + chan;
  float4 v0 = *(const float4*)src;
  float4 v1 = *(const float4*)(src + 4);
  float vv[8] = {v0.x, v0.y, v0.z, v0.w, v1.x, v1.y, v1.z, v1.w};
  f16x8 h, l;
  #pragma unroll
  for (int j = 0; j < 8; ++j) {
    f16 hh = (f16)vv[j];
    h[j] = hh;
    l[j] = (f16)(vv[j] - (float)hh);
  }
  size_t o = xoff(row, chan);
  *(f16x8*)(Hi + o) = h;
  *(f16x8*)(Lo + o) = l;
}

// ---------------- fused LN (z picks predictor set) ----------------
__global__ __launch_bounds__(256) void lnF(
    f16* __restrict__ P0h, f16* __restrict__ P0l,
    f16* __restrict__ P1h, f16* __restrict__ P1l,
    const float* __restrict__ g0, const float* __restrict__ be0,
    const float* __restrict__ g1, const float* __restrict__ be1)
{
  int z = blockIdx.y;
  f16* Ph = z ? P1h : P0h;
  f16* Pl = z ? P1l : P0l;
  const float* g  = z ? g1 : g0;
  const float* be = z ? be1 : be0;
  int row  = blockIdx.x * 4 + (threadIdx.x >> 6);
  int lane = threadIdx.x & 63;
  size_t o = xoff(row, lane * 4);
  f16x4 h = *(const f16x4*)(Ph + o);
  f16x4 l = *(const f16x4*)(Pl + o);
  float v[4];
  #pragma unroll
  for (int j = 0; j < 4; ++j) v[j] = (float)h[j] + (float)l[j];
  float s = v[0] + v[1] + v[2] + v[3];
  float q = v[0]*v[0] + v[1]*v[1] + v[2]*v[2] + v[3]*v[3];
  #pragma unroll
  for (int d = 32; d > 0; d >>= 1) { s += __shfl_xor(s, d); q += __shfl_xor(q, d); }
  float mean = s * (1.f / 256.f);
  float var  = q * (1.f / 256.f) - mean * mean;
  float inv  = 1.0f / sqrtf(var + 1e-5f);
  float4 gg = *(const float4*)(g + lane * 4);
  float4 bb = *(const float4*)(be + lane * 4);
  float gv[4] = {gg.x, gg.y, gg.z, gg.w};
  float bv[4] = {bb.x, bb.y, bb.z, bb.w};
  #pragma unroll
  for (int j = 0; j < 4; ++j) {
    float oo = (v[j] - mean) * inv * gv[j] + bv[j];
    f16 hh = (f16)oo;
    h[j] = hh;
    l[j] = (f16)(oo - (float)hh);
  }
  *(f16x4*)(Ph + o) = h;
  *(f16x4*)(Pl + o) = l;
}

// ------- fused LN+head for dur (z=0) and pit (z=1, + bucket + emb add) -------
__global__ __launch_bounds__(256) void lnheadD(
    const f16* __restrict__ U0h, const f16* __restrict__ U0l,
    const f16* __restrict__ U1h, const f16* __restrict__ U1l,
    const float* __restrict__ g0, const float* __restrict__ be0,
    const float* __restrict__ wl0, const float* __restrict__ bl0,
    const float* __restrict__ g1, const float* __restrict__ be1,
    const float* __restrict__ wl1, const float* __restrict__ bl1,
    const unsigned char* __restrict__ mask, const float* __restrict__ pc,
    float* __restrict__ o_ldur, float* __restrict__ pred_d,
    float* __restrict__ o_pit,
    const float* __restrict__ pbins, const float* __restrict__ pemb,
    const f16* __restrict__ XPh, const f16* __restrict__ XPl,
    f16* __restrict__ X1h, f16* __restrict__ X1l)
{
  int z = blockIdx.y;
  int row  = blockIdx.x * 4 + (threadIdx.x >> 6);
  int lane = threadIdx.x & 63;
  size_t o = xoff(row, lane * 4);
  const f16* Uh = z ? U1h : U0h;
  const f16* Ul = z ? U1l : U0l;
  f16x4 h = *(const f16x4*)(Uh + o);
  f16x4 l = *(const f16x4*)(Ul + o);
  float v[4];
  #pragma unroll
  for (int j = 0; j < 4; ++j) v[j] = (float)h[j] + (float)l[j];
  float s = v[0] + v[1] + v[2] + v[3];
  float q = v[0]*v[0] + v[1]*v[1] + v[2]*v[2] + v[3]*v[3];
  #pragma unroll
  for (int d = 32; d > 0; d >>= 1) { s += __shfl_xor(s, d); q += __shfl_xor(q, d); }
  float mean = s * (1.f / 256.f);
  float var  = q * (1.f / 256.f) - mean * mean;
  float inv  = 1.0f / sqrtf(var + 1e-5f);
  const float* g  = z ? g1  : g0;
  const float* be = z ? be1 : be0;
  const float* wl = z ? wl1 : wl0;
  float4 gg = *(const float4*)(g + lane * 4);
  float4 bb = *(const float4*)(be + lane * 4);
  float4 ww = *(const float4*)(wl + lane * 4);
  float gv[4] = {gg.x, gg.y, gg.z, gg.w};
  float bv[4] = {bb.x, bb.y, bb.z, bb.w};
  float wv[4] = {ww.x, ww.y, ww.z, ww.w};
  float acc = 0.f;
  #pragma unroll
  for (int j = 0; j < 4; ++j)
    acc += ((v[j] - mean) * inv * gv[j] + bv[j]) * wv[j];
  #pragma unroll
  for (int d = 32; d > 0; d >>= 1) acc += __shfl_xor(acc, d);
  float r = acc + (z ? bl1 : bl0)[0];
  if (mask[row]) r = 0.f;
  if (z == 0) {
    if (lane == 0) { o_ldur[row] = r; pred_d[row] = r; }
  } else {
    r *= pc[0];
    if (lane == 0) o_pit[row] = r;
    int lo = 0, hi = 255;
    while (lo < hi) { int mid = (lo + hi) >> 1; if (pbins[mid] < r) lo = mid + 1; else hi = mid; }
    f16x4 xh = *(const f16x4*)(XPh + o);
    f16x4 xl = *(const f16x4*)(XPl + o);
    float4 e = *(const float4*)(pemb + (size_t)lo * HH + lane * 4);
    float ev[4] = {e.x, e.y, e.z, e.w};
    #pragma unroll
    for (int j = 0; j < 4; ++j) {
      float oo = (float)xh[j] + (float)xl[j] + ev[j];
      f16 hh = (f16)oo;
      xh[j] = hh;
      xl[j] = (f16)(oo - (float)hh);
    }
    *(f16x4*)(X1h + o) = xh;
    *(f16x4*)(X1l + o) = xl;
  }
}

// ------- energy final: LN + head + bucket + emb add (plane input) -------
__global__ __launch_bounds__(256) void lnheadE(
    const f16* __restrict__ Uh, const f16* __restrict__ Ul,
    const float* __restrict__ g, const float* __restrict__ be,
    const float* __restrict__ wl, const float* __restrict__ bl,
    const unsigned char* __restrict__ mask, const float* __restrict__ ec,
    float* __restrict__ o_ene,
    const float* __restrict__ ebins, const float* __restrict__ eemb,
    const f16* __restrict__ X1h, const f16* __restrict__ X1l,
    f16* __restrict__ X2h, f16* __restrict__ X2l)
{
  int row  = blockIdx.x * 4 + (threadIdx.x >> 6);
  int lane = threadIdx.x & 63;
  size_t o = xoff(row, lane * 4);
  f16x4 h = *(const f16x4*)(Uh + o);
  f16x4 l = *(const f16x4*)(Ul + o);
  float v[4];
  #pragma unroll
  for (int j = 0; j < 4; ++j) v[j] = (float)h[j] + (float)l[j];
  float s = v[0] + v[1] + v[2] + v[3];
  float q = v[0]*v[0] + v[1]*v[1] + v[2]*v[2] + v[3]*v[3];
  #pragma unroll
  for (int d = 32; d > 0; d >>= 1) { s += __shfl_xor(s, d); q += __shfl_xor(q, d); }
  float mean = s * (1.f / 256.f);
  float var  = q * (1.f / 256.f) - mean * mean;
  float inv  = 1.0f / sqrtf(var + 1e-5f);
  float4 gg = *(const float4*)(g + lane * 4);
  float4 bb = *(const float4*)(be + lane * 4);
  float4 ww = *(const float4*)(wl + lane * 4);
  float gv[4] = {gg.x, gg.y, gg.z, gg.w};
  float bv[4] = {bb.x, bb.y, bb.z, bb.w};
  float wv[4] = {ww.x, ww.y, ww.z, ww.w};
  float acc = 0.f;
  #pragma unroll
  for (int j = 0; j < 4; ++j)
    acc += ((v[j] - mean) * inv * gv[j] + bv[j]) * wv[j];
  #pragma unroll
  for (int d = 32; d > 0; d >>= 1) acc += __shfl_xor(acc, d);
  float r = acc + bl[0];
  if (mask[row]) r = 0.f;
  r *= ec[0];
  if (lane == 0) o_ene[row] = r;
  int lo = 0, hi = 255;
  while (lo < hi) { int mid = (lo + hi) >> 1; if (ebins[mid] < r) lo = mid + 1; else hi = mid; }
  f16x4 xh = *(const f16x4*)(X1h + o);
  f16x4 xl = *(const f16x4*)(X1l + o);
  float4 e = *(const float4*)(eemb + (size_t)lo * HH + lane * 4);
  float ev[4] = {e.x, e.y, e.z, e.w};
  #pragma unroll
  for (int j = 0; j < 4; ++j) {
    float oo = (float)xh[j] + (float)xl[j] + ev[j];
    f16 hh = (f16)oo;
    xh[j] = hh;
    xl[j] = (f16)(oo - (float)hh);
  }
  *(f16x4*)(X2h + o) = xh;
  *(f16x4*)(X2l + o) = xl;
}

// ---------------- duration post: dur, cumsum, mel_len ----------------
__global__ __launch_bounds__(512) void dur_post(
    const float* __restrict__ logdur, const float* __restrict__ dc,
    float* __restrict__ out_dur, float* __restrict__ out_mel_len,
    int* __restrict__ cum_ws, int* __restrict__ mel_len_ws)
{
  __shared__ int wsum[8];
  int b = blockIdx.x, t = threadIdx.x;
  float ld = logdur[b * SS + t];
  float d  = fmaxf(rintf(expf(ld) - 1.f) * dc[0], 0.f);
  out_dur[b * SS + t] = d;
  int di = (int)d;
  int lane = t & 63, w = t >> 6;
  int x = di;
  #pragma unroll
  for (int dd = 1; dd < 64; dd <<= 1) {
    int n = __shfl_up(x, dd);
    if (lane >= dd) x += n;
  }
  if (lane == 63) wsum[w] = x;
  __syncthreads();
  int off = 0;
  for (int i = 0; i < w; ++i) off += wsum[i];
  x += off;
  cum_ws[b * SS + t] = x;
  if (t == SS - 1) {
    int ml = min(x, MAXMEL);
    mel_len_ws[b] = ml;
    out_mel_len[b] = (float)ml;
  }
}

// ---------------- length regulator from X''' planes ----------------
__global__ __launch_bounds__(256) void gather_planes(
    const f16* __restrict__ Xhi, const f16* __restrict__ Xlo,
    const int* __restrict__ cum, const int* __restrict__ mel_len_ws,
    float* __restrict__ out_x, float* __restrict__ out_mask)
{
  __shared__ int c[SS];
  int b   = blockIdx.y;
  int tid = threadIdx.x;
  c[tid]       = cum[b * SS + tid];
  c[tid + 256] = cum[b * SS + tid + 256];
  __syncthreads();
  int w = tid >> 6, lane = tid & 63;
  int t = blockIdx.x * 4 + w;
  int lo = 0, hi = SS;
  while (lo < hi) { int mid = (lo + hi) >> 1; if (c[mid] <= t) lo = mid + 1; else hi = mid; }
  int idx = min(lo, SS - 1);
  int ml  = mel_len_ws[b];
  bool m  = (t >= ml);
  float4 v = make_float4(0.f, 0.f, 0.f, 0.f);
  if (!m) {
    size_t o = xoff(b * SS + idx, lane * 4);
    f16x4 xh = *(const f16x4*)(Xhi + o);
    f16x4 xl = *(const f16x4*)(Xlo + o);
    v.x = (float)xh[0] + (float)xl[0];
    v.y = (float)xh[1] + (float)xl[1];
    v.z = (float)xh[2] + (float)xl[2];
    v.w = (float)xh[3] + (float)xl[3];
  }
  *(float4*)(out_x + ((size_t)b * MAXMEL + t) * HH + lane * 4) = v;
  if (lane == 0) out_mask[b * MAXMEL + t] = m ? 1.f : 0.f;
}

// ---------------- launcher ----------------
extern "C" void kernel_launch(void* const* d_in, const int* in_sizes, int n_in,
                              void* d_out, int out_size, void* d_ws, size_t ws_size,
                              hipStream_t stream) {
  const float* x     = (const float*)d_in[0];
  const unsigned char* smask = (const unsigned char*)d_in[1];
  const float* pc    = (const float*)d_in[2];
  const float* ec    = (const float*)d_in[3];
  const float* dc    = (const float*)d_in[4];
  const float* pbins = (const float*)d_in[5];
  const float* ebins = (const float*)d_in[6];
  const float* pemb  = (const float*)d_in[7];
  const float* eemb  = (const float*)d_in[8];

  float* out = (float*)d_out;
  float* o_xexp  = out;
  float* o_pit   = out + (size_t)16777216;
  float* o_ene   = o_pit + 16384;
  float* o_ldur  = o_ene + 16384;
  float* o_dur   = o_ldur + 16384;
  float* o_mlen  = o_dur + 16384;
  float* o_mmask = o_mlen + 32;

  const size_t PL = (size_t)MM * HH;       // f16 elems per plane
  f16* p = (f16*)d_ws;
  f16 *XPh = p,        *XPl = p + PL;
  f16 *Tdh = p + 2*PL, *Tdl = p + 3*PL;
  f16 *Tph = p + 4*PL, *Tpl = p + 5*PL;
  f16 *Udh = p + 6*PL, *Udl = p + 7*PL;
  f16 *Uph = p + 8*PL, *Upl = p + 9*PL;
  f16 *X1h = p + 10*PL, *X1l = p + 11*PL;
  f16 *Teh = p + 12*PL, *Tel = p + 13*PL;
  f16 *Ueh = p + 14*PL, *Uel = p + 15*PL;
  f16 *X2h = p + 16*PL, *X2l = p + 17*PL;
  f16* Wt  = p + 18*PL;                    // 12 packed planes of WSZ
  float* pred_d = (float*)(Wt + 12 * WSZ);
  int*   cum = (int*)(pred_d + MM);
  int*   mlw = cum + MM;

  #define WPH(i) (Wt + (size_t)(i) * 2 * WSZ)
  #define WPL(i) (Wt + (size_t)(i) * 2 * WSZ + WSZ)

  // weights: 0=dur w1(9), 1=dur w2(13), 2=pit w1(19), 3=pit w2(23), 4=ene w1(29), 5=ene w2(33)
  wsplit6<<<dim3(96, 6), 256, 0, stream>>>(
      (const float*)d_in[9], (const float*)d_in[13], (const float*)d_in[19],
      (const float*)d_in[23], (const float*)d_in[29], (const float*)d_in[33], Wt);

  split2<<<2048, 256, 0, stream>>>(x, XPh, XPl);

  dim3 cgrid2(256, 2, 2);    // dur+pit fused
  dim3 cgrid1(256, 2, 1);    // energy alone
  dim3 rgrid(MM / 4);
  dim3 rgrid2(MM / 4, 2);

  // fused dur+pit conv1
  conv64<<<cgrid2, 256, 0, stream>>>(
      XPh, XPl, XPh, XPl,
      WPH(0), WPL(0), WPH(2), WPL(2),
      (const float*)d_in[10], (const float*)d_in[20],
      Tdh, Tdl, Tph, Tpl);
  lnF<<<rgrid2, 256, 0, stream>>>(Tdh, Tdl, Tph, Tpl,
      (const float*)d_in[11], (const float*)d_in[12],
      (const float*)d_in[21], (const float*)d_in[22]);
  // fused dur+pit conv2
  conv64<<<cgrid2, 256, 0, stream>>>(
      Tdh, Tdl, Tph, Tpl,
      WPH(1), WPL(1), WPH(3), WPL(3),
      (const float*)d_in[14], (const float*)d_in[24],
      Udh, Udl, Uph, Upl);
  lnheadD<<<rgrid2, 256, 0, stream>>>(
      Udh, Udl, Uph, Upl,
      (const float*)d_in[15], (const float*)d_in[16],
      (const float*)d_in[17], (const float*)d_in[18],
      (const float*)d_in[25], (const float*)d_in[26],
      (const float*)d_in[27], (const float*)d_in[28],
      smask, pc, o_ldur, pred_d, o_pit, pbins, pemb,
      XPh, XPl, X1h, X1l);
  dur_post<<<BB, 512, 0, stream>>>(pred_d, dc, o_dur, o_mlen, cum, mlw);

  // energy conv1 (input X1) -> Te
  conv64<<<cgrid1, 256, 0, stream>>>(
      X1h, X1l, X1h, X1l,
      WPH(4), WPL(4), WPH(4), WPL(4),
      (const float*)d_in[30], (const float*)d_in[30],
      Teh, Tel, Teh, Tel);
  lnF<<<dim3(MM / 4, 1), 256, 0, stream>>>(Teh, Tel, Teh, Tel,
      (const float*)d_in[31], (const float*)d_in[32],
      (const float*)d_in[31], (const float*)d_in[32]);
  // energy conv2 -> Ue
  conv64<<<cgrid1, 256, 0, stream>>>(
      Teh, Tel, Teh, Tel,
      WPH(5), WPL(5), WPH(5), WPL(5),
      (const float*)d_in[34], (const float*)d_in[34],
      Ueh, Uel, Ueh, Uel);
  lnheadE<<<rgrid, 256, 0, stream>>>(Ueh, Uel,
      (const float*)d_in[35], (const float*)d_in[36],
      (const float*)d_in[37], (const float*)d_in[38],
      smask, ec, o_ene, ebins, eemb, X1h, X1l, X2h, X2l);

  dim3 ggrid(MAXMEL / 4, BB);
  gather_planes<<<ggrid, 256, 0, stream>>>(X2h, X2l, cum, mlw, o_xexp, o_mmask);

  #undef WPH
  #undef WPL
}